// Round 11
// baseline (268.549 us; speedup 1.0000x reference)
//
#include <hip/hip_runtime.h>

#define N_NODES 100000
#define N_EDGES 1600000
#define D_FEAT 128
#define BUCKETS 1024
#define RPB 98             /* rows per bucket; 1024*98 = 100352 >= 100000 */
#define BKCAP 2048         /* fixed region per bucket; mean 1563, sd ~40, +12sd */
#define BIN_CHUNK 4096
#define BIN_WGS ((N_EDGES + BIN_CHUNK - 1) / BIN_CHUNK)  /* 391 */

#define CONV_ELEMS (N_NODES * D_FEAT / 4)                /* 3.2M float4 */
#define CONV_WGS 2048                                    /* grid-stride, fat blocks */

/* k_bin grid: wprep | bin */
#define WPREP_WGS 16
#define KBIN_WGS (WPREP_WGS + BIN_WGS)

/* fused agg+gemm: 512 threads = 8 waves, 16 rows/block, 2 rows/wave */
#define AGG_STRIDE 68      /* u32 pairs per LDS row (64 + 4 pad) */
#define AGEMM_WGS (N_NODES / 16)                         /* 6250, exact */

typedef unsigned int u32;
typedef unsigned short u16;
typedef __attribute__((ext_vector_type(8))) short bf16x8;
typedef __attribute__((ext_vector_type(4))) float f32x4;

__device__ inline float bfbits2f(u32 hi) { union { u32 u; float f; } v; v.u = hi; return v.f; }
__device__ inline float bflo(u32 pair) { return bfbits2f(pair << 16); }
__device__ inline float bfhi(u32 pair) { return bfbits2f(pair & 0xFFFF0000u); }
__device__ inline u16 f2bf(float f) {
  union { float f; u32 u; } v; v.f = f;
  u32 r = v.u + 0x7FFFu + ((v.u >> 16) & 1u);
  return (u16)(r >> 16);
}
__device__ inline int clampN(int v) { return ((unsigned)v < N_NODES) ? v : 0; }

// ---- conv: x f32 -> bf16 pairs. Zero LDS, grid-stride fat blocks.
//      Block 0 also zeroes gcur (replaces the memset dispatch).
__global__ __launch_bounds__(256) void k_conv(const float4* __restrict__ x4,
                                              uint2* __restrict__ xb2,
                                              int* __restrict__ gcur) {
  if (blockIdx.x == 0) {
#pragma unroll
    for (int k = 0; k < BUCKETS / 256; k++) gcur[k * 256 + threadIdx.x] = 0;
  }
  for (int i = blockIdx.x * 256 + threadIdx.x; i < CONV_ELEMS; i += CONV_WGS * 256) {
    float4 v = x4[i];
    uint2 o;
    o.x = (u32)f2bf(v.x) | ((u32)f2bf(v.y) << 16);
    o.y = (u32)f2bf(v.z) | ((u32)f2bf(v.w) << 16);
    xb2[i] = o;
  }
}

// ---- weight prep + edge binning (LDS-heavy phases only) ----
__global__ __launch_bounds__(256) void k_bin(const float* __restrict__ Wself,
                                             const float* __restrict__ Wnb,
                                             u16* __restrict__ Wbf,
                                             const int* __restrict__ ei,
                                             int* __restrict__ gcur,
                                             u32* __restrict__ binrec) {
  __shared__ int hist[BUCKETS], pref[BUCKETS], lcur[BUCKETS], ps[256];
  __shared__ u32 stag[BIN_CHUNK];
  __shared__ u16 sbkt[BIN_CHUNK];
  int b = blockIdx.x;
  int tid = threadIdx.x;
  if (b < WPREP_WGS) {
    int f = b * 256 + tid;   // 4096 entries
    int lane = f & 63, nt = (f >> 6) & 7, kk = (f >> 9) & 3, t = f >> 11;
    int q = lane >> 4, l16 = lane & 15;
    const float* W = t ? Wnb : Wself;
    int n = nt * 16 + l16;
    int k0 = (kk * 4 + q) * 8;
    u16 tmp[8];
#pragma unroll
    for (int j = 0; j < 8; j++) tmp[j] = f2bf(W[(k0 + j) * 128 + n]);
    uint4 o;
    o.x = (u32)tmp[0] | ((u32)tmp[1] << 16);
    o.y = (u32)tmp[2] | ((u32)tmp[3] << 16);
    o.z = (u32)tmp[4] | ((u32)tmp[5] << 16);
    o.w = (u32)tmp[6] | ((u32)tmp[7] << 16);
    *(uint4*)(Wbf + (long)f * 8) = o;
  } else {
    // ---- binning: WG-local LDS counting sort, bucket-contiguous flush ----
    int wb = b - WPREP_WGS;
    long e0 = (long)wb * BIN_CHUNK;
    for (int k = tid; k < BUCKETS; k += 256) { hist[k] = 0; lcur[k] = 0; }
    __syncthreads();
    int rows[BIN_CHUNK / 256];
#pragma unroll
    for (int j = 0; j < BIN_CHUNK / 256; j++) {
      long e = e0 + j * 256 + tid;
      int r = (e < N_EDGES) ? clampN(ei[e]) : -1;
      rows[j] = r;
      if (r >= 0) atomicAdd(&hist[r / RPB], 1);
    }
    __syncthreads();
    // scan 1024 bins with 256 threads (4 bins/thread)
    int v0 = hist[4 * tid + 0], v1 = hist[4 * tid + 1];
    int v2 = hist[4 * tid + 2], v3 = hist[4 * tid + 3];
    int s = v0 + v1 + v2 + v3;
    ps[tid] = s;
    __syncthreads();
    for (int off = 1; off < 256; off <<= 1) {
      int t = (tid >= off) ? ps[tid - off] : 0;
      __syncthreads();
      ps[tid] += t;
      __syncthreads();
    }
    int excl = ps[tid] - s;
    pref[4 * tid + 0] = excl;
    pref[4 * tid + 1] = excl + v0;
    pref[4 * tid + 2] = excl + v0 + v1;
    pref[4 * tid + 3] = excl + v0 + v1 + v2;
    // reserve global ranges; reuse hist as absolute gbase
    hist[4 * tid + 0] = (4 * tid + 0) * BKCAP + (v0 ? atomicAdd(&gcur[4 * tid + 0], v0) : 0);
    hist[4 * tid + 1] = (4 * tid + 1) * BKCAP + (v1 ? atomicAdd(&gcur[4 * tid + 1], v1) : 0);
    hist[4 * tid + 2] = (4 * tid + 2) * BKCAP + (v2 ? atomicAdd(&gcur[4 * tid + 2], v2) : 0);
    hist[4 * tid + 3] = (4 * tid + 3) * BKCAP + (v3 ? atomicAdd(&gcur[4 * tid + 3], v3) : 0);
    int total = ps[255];
    __syncthreads();
#pragma unroll
    for (int j = 0; j < BIN_CHUNK / 256; j++) {
      int r = rows[j];
      if (r < 0) continue;
      long e = e0 + j * 256 + tid;
      int c = clampN(ei[N_EDGES + e]);
      int bk = r / RPB;
      int rl = r - bk * RPB;
      int pos = pref[bk] + atomicAdd(&lcur[bk], 1);
      stag[pos] = ((u32)rl << 17) | (u32)c;
      sbkt[pos] = (u16)bk;
    }
    __syncthreads();
    for (int i = tid; i < total; i += 256) {
      int bk = sbkt[i];
      int idx = hist[bk] + (i - pref[bk]);          // hist = absolute gbase
      if (idx < (bk + 1) * BKCAP) binrec[idx] = stag[i];   // overflow guard
    }
  }
}

// ---- merged CSR: per-bucket hist + scan -> deg/row_start/dis, then
//      in-LDS placement -> coalesced cn (col only; norm computed in agg).
__global__ __launch_bounds__(256) void k_csr(const int* __restrict__ gcur,
                                             const u32* __restrict__ binrec,
                                             int* __restrict__ deg,
                                             int* __restrict__ row_start,
                                             float* __restrict__ dis,
                                             int* __restrict__ cn) {
  __shared__ int h[128];      // per-row counts (RPB=98, padded); scan in-place
  __shared__ int cur[128];    // placement cursors
  __shared__ int win[BKCAP];  // 8 KB staging window
  int tid = threadIdx.x;
  int b = blockIdx.x;
  int r0 = b * RPB;
  int nrows = N_NODES - r0; if (nrows > RPB) nrows = RPB;
  int base = b * BKCAP;
  int cnt = gcur[b]; if (cnt > BKCAP) cnt = BKCAP;
  if (tid < 128) h[tid] = 0;
  __syncthreads();
  for (int i = tid; i < cnt; i += 256) {
    u32 rec = binrec[base + i];
    atomicAdd(&h[rec >> 17], 1);
  }
  __syncthreads();
  int v = (tid < 128) ? h[tid] : 0;
  __syncthreads();
  for (int off = 1; off < 128; off <<= 1) {
    int t = (tid >= off && tid < 128) ? h[tid - off] : 0;
    __syncthreads();
    if (tid < 128) h[tid] += t;
    __syncthreads();
  }
  int excl = (tid < 128) ? (h[tid] - v) : 0;
  if (tid < 128) cur[tid] = excl;
  if (tid < nrows) {
    int r = r0 + tid;
    deg[r] = v;
    row_start[r] = base + excl;
    dis[r] = v ? rsqrtf((float)v) : 0.0f;
  }
  __syncthreads();
  for (int i = tid; i < cnt; i += 256) {
    u32 rec = binrec[base + i];
    int rl = rec >> 17;
    int p = atomicAdd(&cur[rl], 1);
    win[p] = (int)(rec & 0x1FFFF);
  }
  __syncthreads();
  for (int i = tid; i < cnt; i += 256) cn[base + i] = win[i];
}

// -------- fused aggregation + GEMM --------
// 512 threads = 8 waves; 16 rows/block; 2 rows/wave (pair-smoothing of
// the barrier imbalance; R7's failure was 16 seq rows/wave + 17.4KB LDS).
// Phase 1 per row = R10's verified k_agg body (batch-8, exact tiers,
// on-the-fly norm) -> bf16 pairs in LDS (4.4 KB).
// Phase 2: wave w owns col-tile nt=w: A from xb global + LDS agg
// (fragment layout verified in R7), B from Wbf, 8 MFMA, bias, out.
// Deletes the 51.2 MB aggb round-trip + the k_gemm dispatch.
__global__ __launch_bounds__(512) void k_aggemm(const int* __restrict__ row_start,
                                                const int* __restrict__ deg,
                                                const float* __restrict__ dis,
                                                const int* __restrict__ cn,
                                                const u32* __restrict__ xb /* pairs, stride 64 */,
                                                const u16* __restrict__ Wbf,
                                                const float* __restrict__ bias,
                                                float* __restrict__ out) {
  __shared__ u32 agg[16 * AGG_STRIDE];   // 4.4 KB
  int wave = threadIdx.x >> 6, lane = threadIdx.x & 63;
  int nb0 = blockIdx.x * 16;

  // ---- phase 1: 2 rows per wave ----
#pragma unroll 1
  for (int t = 0; t < 2; t++) {
    int rl = wave * 2 + t;
    int r = nb0 + rl;                      // grid exact: r < N_NODES always
    int start = row_start[r];
    int cnt = deg[r];
    float dr = dis[r];
    float a0 = 0.f, a1 = 0.f, b0 = 0.f, b1 = 0.f;
    int i = 0;
    for (; i + 8 <= cnt; i += 8) {
      int c[8];
      u32 g[8];
      float nc[8];
#pragma unroll
      for (int j = 0; j < 8; j++) c[j] = cn[start + i + j];
#pragma unroll
      for (int j = 0; j < 8; j++) g[j] = xb[(long)c[j] * 64 + lane];
#pragma unroll
      for (int j = 0; j < 8; j++) nc[j] = dis[c[j]];
#pragma unroll
      for (int j = 0; j < 8; j++) {
        float n = dr * nc[j];
        if (j & 1) { b0 += n * bflo(g[j]); b1 += n * bfhi(g[j]); }
        else       { a0 += n * bflo(g[j]); a1 += n * bfhi(g[j]); }
      }
    }
    for (; i + 2 <= cnt; i += 2) {
      int c0 = cn[start + i], c1 = cn[start + i + 1];
      u32 g0 = xb[(long)c0 * 64 + lane];
      u32 g1 = xb[(long)c1 * 64 + lane];
      float n0 = dr * dis[c0], n1 = dr * dis[c1];
      a0 += n0 * bflo(g0); a1 += n0 * bfhi(g0);
      b0 += n1 * bflo(g1); b1 += n1 * bfhi(g1);
    }
    if (i < cnt) {
      int c0 = cn[start + i];
      u32 g0 = xb[(long)c0 * 64 + lane];
      float n0 = dr * dis[c0];
      a0 += n0 * bflo(g0); a1 += n0 * bfhi(g0);
    }
    a0 += b0; a1 += b1;
    agg[rl * AGG_STRIDE + lane] = (u32)f2bf(a0) | ((u32)f2bf(a1) << 16);
  }
  __syncthreads();

  // ---- phase 2: wave w = col-tile nt=w for the 16-row block ----
  int q = lane >> 4, l16 = lane & 15;
  int nt = wave;
  int ncol = nt * 16 + l16;
  float bv = bias[ncol];
  const u16* xb16 = (const u16*)xb;

  f32x4 acc = {0.f, 0.f, 0.f, 0.f};
#pragma unroll
  for (int kk = 0; kk < 4; kk++) {
    bf16x8 ax = *(const bf16x8*)(xb16 + (long)(nb0 + l16) * D_FEAT + q * 8 + kk * 32);
    bf16x8 bs = *(const bf16x8*)(Wbf + (long)((kk * 8 + nt) * 64 + lane) * 8);
    acc = __builtin_amdgcn_mfma_f32_16x16x32_bf16(ax, bs, acc, 0, 0, 0);
  }
#pragma unroll
  for (int kk = 0; kk < 4; kk++) {
    bf16x8 av = *(const bf16x8*)((const u16*)&agg[l16 * AGG_STRIDE + q * 4 + kk * 16]);
    bf16x8 bn = *(const bf16x8*)(Wbf + (long)(((4 + kk) * 8 + nt) * 64 + lane) * 8);
    acc = __builtin_amdgcn_mfma_f32_16x16x32_bf16(av, bn, acc, 0, 0, 0);
  }
#pragma unroll
  for (int reg = 0; reg < 4; reg++) {
    int nd = nb0 + q * 4 + reg;
    out[(long)nd * D_FEAT + ncol] = acc[reg] + bv;
  }
}

extern "C" void kernel_launch(void* const* d_in, const int* in_sizes, int n_in,
                              void* d_out, int out_size, void* d_ws, size_t ws_size,
                              hipStream_t stream) {
  const float* x = (const float*)d_in[0];
  const int* ei = (const int*)d_in[1];         // int32
  const float* Wself = (const float*)d_in[2];
  const float* Wnb = (const float*)d_in[3];
  const float* bias = (const float*)d_in[4];
  float* out = (float*)d_out;

  auto alignup = [](size_t v) { return (v + 511) & ~(size_t)511; };
  char* p = (char*)d_ws;
  int* deg = (int*)p;            p += alignup((size_t)N_NODES * 4);
  int* row_start = (int*)p;      p += alignup((size_t)N_NODES * 4);
  float* dis = (float*)p;        p += alignup((size_t)N_NODES * 4);
  int* gcur = (int*)p;           p += alignup((size_t)BUCKETS * 4);
  u16* Wbf = (u16*)p;            p += alignup((size_t)4096 * 8 * 2);          // 64 KB
  int* cn = (int*)p;             p += alignup((size_t)BUCKETS * BKCAP * 4);   // 8.4 MB
  u16* xb = (u16*)p;             p += alignup((size_t)N_NODES * D_FEAT * 2);  // 25.6 MB
  // ~35 MB of d_ws (aggb eliminated by fusion)
  u32* binrec = (u32*)d_out;     // 8.4 MB staged in d_out; dead before k_aggemm writes it

  k_conv<<<CONV_WGS, 256, 0, stream>>>((const float4*)x, (uint2*)xb, gcur);
  k_bin<<<KBIN_WGS, 256, 0, stream>>>(Wself, Wnb, Wbf, ei, gcur, binrec);
  k_csr<<<BUCKETS, 256, 0, stream>>>(gcur, binrec, deg, row_start, dis, cn);
  k_aggemm<<<AGEMM_WGS, 512, 0, stream>>>(row_start, deg, dis, cn, (const u32*)xb, Wbf, bias, out);
}

// Round 12
// 244.193 us; speedup vs baseline: 1.0997x; 1.0997x over previous
//
#include <hip/hip_runtime.h>

#define N_NODES 100000
#define N_EDGES 1600000
#define D_FEAT 128
#define BUCKETS 512
#define RPB 196            /* rows per bucket; 512*196 = 100352 >= 100000 */
#define BKCAP 4096         /* fixed region; mean 3136, sd ~56, +17sd */
#define BIN_CHUNK 8192
#define BIN_WGS ((N_EDGES + BIN_CHUNK - 1) / BIN_CHUNK)  /* 196 */

#define CONV_ELEMS (N_NODES * D_FEAT / 4)                /* 3.2M float4 */
#define CONV_WGS 2048                                    /* grid-stride, fat blocks */
#define WPREP_WGS 16
#define KCONV_WGS (CONV_WGS + WPREP_WGS)

typedef unsigned int u32;
typedef unsigned short u16;
typedef __attribute__((ext_vector_type(8))) short bf16x8;
typedef __attribute__((ext_vector_type(4))) float f32x4;

__device__ inline float bfbits2f(u32 hi) { union { u32 u; float f; } v; v.u = hi; return v.f; }
__device__ inline float bflo(u32 pair) { return bfbits2f(pair << 16); }
__device__ inline float bfhi(u32 pair) { return bfbits2f(pair & 0xFFFF0000u); }
__device__ inline u16 f2bf(float f) {
  union { float f; u32 u; } v; v.f = f;
  u32 r = v.u + 0x7FFFu + ((v.u >> 16) & 1u);
  return (u16)(r >> 16);
}
__device__ inline int clampN(int v) { return ((unsigned)v < N_NODES) ? v : 0; }

// ---- conv + weight prep (both zero-LDS; R9 lesson: never co-resident
//      with a fat-LDS branch). Block 0 also zeroes gcur (no memset dispatch).
__global__ __launch_bounds__(256) void k_conv(const float4* __restrict__ x4,
                                              uint2* __restrict__ xb2,
                                              const float* __restrict__ Wself,
                                              const float* __restrict__ Wnb,
                                              u16* __restrict__ Wbf,
                                              int* __restrict__ gcur) {
  int tid = threadIdx.x;
  if (blockIdx.x >= CONV_WGS) {
    int f = (blockIdx.x - CONV_WGS) * 256 + tid;   // 4096 entries
    int lane = f & 63, nt = (f >> 6) & 7, kk = (f >> 9) & 3, t = f >> 11;
    int q = lane >> 4, l16 = lane & 15;
    const float* W = t ? Wnb : Wself;
    int n = nt * 16 + l16;
    int k0 = (kk * 4 + q) * 8;
    u16 tmp[8];
#pragma unroll
    for (int j = 0; j < 8; j++) tmp[j] = f2bf(W[(k0 + j) * 128 + n]);
    uint4 o;
    o.x = (u32)tmp[0] | ((u32)tmp[1] << 16);
    o.y = (u32)tmp[2] | ((u32)tmp[3] << 16);
    o.z = (u32)tmp[4] | ((u32)tmp[5] << 16);
    o.w = (u32)tmp[6] | ((u32)tmp[7] << 16);
    *(uint4*)(Wbf + (long)f * 8) = o;
    return;
  }
  if (blockIdx.x == 0) {
#pragma unroll
    for (int k = 0; k < BUCKETS / 256; k++) gcur[k * 256 + tid] = 0;
  }
  for (int i = blockIdx.x * 256 + tid; i < CONV_ELEMS; i += CONV_WGS * 256) {
    float4 v = x4[i];
    uint2 o;
    o.x = (u32)f2bf(v.x) | ((u32)f2bf(v.y) << 16);
    o.y = (u32)f2bf(v.z) | ((u32)f2bf(v.w) << 16);
    xb2[i] = o;
  }
}

// ---- edge binning: WG-local LDS counting sort, bucket-contiguous flush.
//      512 buckets x 8192-edge chunks -> flush segments avg 16 recs = 64 B
//      (R10's 1024x4096 gave 16 B fragments: 4x write amplification).
__global__ __launch_bounds__(256) void k_bin(const int* __restrict__ ei,
                                             int* __restrict__ gcur,
                                             u32* __restrict__ binrec) {
  __shared__ int hist[BUCKETS], pref[BUCKETS], lcur[BUCKETS], ps[256];
  __shared__ u32 stag[BIN_CHUNK];
  __shared__ u16 sbkt[BIN_CHUNK];
  int tid = threadIdx.x;
  long e0 = (long)blockIdx.x * BIN_CHUNK;
  for (int k = tid; k < BUCKETS; k += 256) { hist[k] = 0; lcur[k] = 0; }
  __syncthreads();
  int rows[BIN_CHUNK / 256];
#pragma unroll
  for (int j = 0; j < BIN_CHUNK / 256; j++) {
    long e = e0 + j * 256 + tid;
    int r = (e < N_EDGES) ? clampN(ei[e]) : -1;
    rows[j] = r;
    if (r >= 0) atomicAdd(&hist[r / RPB], 1);
  }
  __syncthreads();
  // scan 512 bins with 256 threads (2 bins/thread)
  int v0 = hist[2 * tid], v1 = hist[2 * tid + 1];
  int s = v0 + v1;
  ps[tid] = s;
  __syncthreads();
  for (int off = 1; off < 256; off <<= 1) {
    int t = (tid >= off) ? ps[tid - off] : 0;
    __syncthreads();
    ps[tid] += t;
    __syncthreads();
  }
  int excl = ps[tid] - s;
  pref[2 * tid] = excl;
  pref[2 * tid + 1] = excl + v0;
  // reserve global ranges; reuse hist as absolute gbase
  hist[2 * tid] = (2 * tid) * BKCAP + (v0 ? atomicAdd(&gcur[2 * tid], v0) : 0);
  hist[2 * tid + 1] = (2 * tid + 1) * BKCAP + (v1 ? atomicAdd(&gcur[2 * tid + 1], v1) : 0);
  int total = ps[255];
  __syncthreads();
#pragma unroll
  for (int j = 0; j < BIN_CHUNK / 256; j++) {
    int r = rows[j];
    if (r < 0) continue;
    long e = e0 + j * 256 + tid;
    int c = clampN(ei[N_EDGES + e]);
    int bk = r / RPB;
    int rl = r - bk * RPB;
    int pos = pref[bk] + atomicAdd(&lcur[bk], 1);
    stag[pos] = ((u32)rl << 17) | (u32)c;
    sbkt[pos] = (u16)bk;
  }
  __syncthreads();
  for (int i = tid; i < total; i += 256) {
    int bk = sbkt[i];
    int idx = hist[bk] + (i - pref[bk]);            // hist = absolute gbase
    if (idx < (bk + 1) * BKCAP) binrec[idx] = stag[i];   // overflow guard
  }
}

// ---- merged CSR: per-bucket hist + scan -> deg/row_start/dis, then
//      in-LDS placement -> coalesced cn (col only; norm computed in k_agg).
//      512 WGs x ~3136 records, ~18 KB LDS.
__global__ __launch_bounds__(256) void k_csr(const int* __restrict__ gcur,
                                             const u32* __restrict__ binrec,
                                             int* __restrict__ deg,
                                             int* __restrict__ row_start,
                                             float* __restrict__ dis,
                                             int* __restrict__ cn) {
  __shared__ int h[256];      // per-row counts (RPB=196, padded); scan in-place
  __shared__ int cur[256];    // placement cursors
  __shared__ int win[BKCAP];  // 16 KB staging window
  int tid = threadIdx.x;
  int b = blockIdx.x;
  int r0 = b * RPB;
  int nrows = N_NODES - r0; if (nrows > RPB) nrows = RPB; if (nrows < 0) nrows = 0;
  int base = b * BKCAP;
  int cnt = gcur[b]; if (cnt > BKCAP) cnt = BKCAP;
  h[tid] = 0;
  __syncthreads();
  for (int i = tid; i < cnt; i += 256) {
    u32 rec = binrec[base + i];
    atomicAdd(&h[rec >> 17], 1);
  }
  __syncthreads();
  int v = h[tid];
  __syncthreads();
  for (int off = 1; off < 256; off <<= 1) {
    int t = (tid >= off) ? h[tid - off] : 0;
    __syncthreads();
    h[tid] += t;
    __syncthreads();
  }
  int excl = h[tid] - v;
  cur[tid] = excl;
  if (tid < nrows) {
    int r = r0 + tid;
    deg[r] = v;
    row_start[r] = base + excl;
    dis[r] = v ? rsqrtf((float)v) : 0.0f;
  }
  __syncthreads();
  for (int i = tid; i < cnt; i += 256) {
    u32 rec = binrec[base + i];
    int rl = rec >> 17;
    int p = atomicAdd(&cur[rl], 1);
    win[p] = (int)(rec & 0x1FFFF);
  }
  __syncthreads();
  for (int i = tid; i < cnt; i += 256) cn[base + i] = win[i];
}

// -------- aggregation: aggb[r] = bf16( sum_e dis[r]*dis[c] * xb[c] ) --------
// R2-proven structure: 1 row/wave, u32/lane full-row gather, batch-8,
// exact tail tiers. norm computed on the fly (dis broadcast loads, L2-hot).
__global__ __launch_bounds__(256) void k_agg(const int* __restrict__ row_start,
                                             const int* __restrict__ deg,
                                             const float* __restrict__ dis,
                                             const int* __restrict__ cn,
                                             const u32* __restrict__ xb /* pairs, stride 64 */,
                                             u32* __restrict__ aggb) {
  int wave = threadIdx.x >> 6, lane = threadIdx.x & 63;
  int r = blockIdx.x * 4 + wave;
  if (r >= N_NODES) return;
  int start = row_start[r];
  int cnt = deg[r];
  float dr = dis[r];
  float a0 = 0.f, a1 = 0.f, b0 = 0.f, b1 = 0.f;
  int i = 0;
  for (; i + 8 <= cnt; i += 8) {
    int c[8];
    u32 g[8];
    float nc[8];
#pragma unroll
    for (int j = 0; j < 8; j++) c[j] = cn[start + i + j];
#pragma unroll
    for (int j = 0; j < 8; j++) g[j] = xb[(long)c[j] * 64 + lane];
#pragma unroll
    for (int j = 0; j < 8; j++) nc[j] = dis[c[j]];
#pragma unroll
    for (int j = 0; j < 8; j++) {
      float n = dr * nc[j];
      if (j & 1) { b0 += n * bflo(g[j]); b1 += n * bfhi(g[j]); }
      else       { a0 += n * bflo(g[j]); a1 += n * bfhi(g[j]); }
    }
  }
  for (; i + 2 <= cnt; i += 2) {
    int c0 = cn[start + i], c1 = cn[start + i + 1];
    u32 g0 = xb[(long)c0 * 64 + lane];
    u32 g1 = xb[(long)c1 * 64 + lane];
    float n0 = dr * dis[c0], n1 = dr * dis[c1];
    a0 += n0 * bflo(g0); a1 += n0 * bfhi(g0);
    b0 += n1 * bflo(g1); b1 += n1 * bfhi(g1);
  }
  if (i < cnt) {
    int c0 = cn[start + i];
    u32 g0 = xb[(long)c0 * 64 + lane];
    float n0 = dr * dis[c0];
    a0 += n0 * bflo(g0); a1 += n0 * bfhi(g0);
  }
  a0 += b0; a1 += b1;
  aggb[(long)r * 64 + lane] = (u32)f2bf(a0) | ((u32)f2bf(a1) << 16);
}

// -------- GEMM: out = x@Wself + agg@Wnb + bias. No LDS; B-frags from global ----
__global__ __launch_bounds__(256) void k_gemm(const u16* __restrict__ xb,
                                              const u16* __restrict__ aggb,
                                              const u16* __restrict__ Wbf,
                                              const float* __restrict__ bias,
                                              float* __restrict__ out) {
  int tid = threadIdx.x;
  int wave = tid >> 6, lane = tid & 63;
  int q = lane >> 4, l16 = lane & 15;
  int w0 = blockIdx.x * 128 + wave * 32;

  bf16x8 ax[2][4], ag[2][4];
#pragma unroll
  for (int mt = 0; mt < 2; mt++) {
    int node = w0 + mt * 16 + l16;
    long aoff = (long)clampN(node) * D_FEAT + q * 8;
#pragma unroll
    for (int kk = 0; kk < 4; kk++) {
      ax[mt][kk] = *(const bf16x8*)(xb + aoff + kk * 32);
      ag[mt][kk] = *(const bf16x8*)(aggb + aoff + kk * 32);
    }
  }

#pragma unroll
  for (int nt = 0; nt < 8; nt++) {
    bf16x8 bs[4], bn[4];
#pragma unroll
    for (int kk = 0; kk < 4; kk++) {
      bs[kk] = *(const bf16x8*)(Wbf + (long)(((0 * 4 + kk) * 8 + nt) * 64 + lane) * 8);
      bn[kk] = *(const bf16x8*)(Wbf + (long)(((1 * 4 + kk) * 8 + nt) * 64 + lane) * 8);
    }
    int ncol = nt * 16 + l16;
    float bv = bias[ncol];
#pragma unroll
    for (int mt = 0; mt < 2; mt++) {
      f32x4 acc = {0.f, 0.f, 0.f, 0.f};
#pragma unroll
      for (int kk = 0; kk < 4; kk++)
        acc = __builtin_amdgcn_mfma_f32_16x16x32_bf16(ax[mt][kk], bs[kk], acc, 0, 0, 0);
#pragma unroll
      for (int kk = 0; kk < 4; kk++)
        acc = __builtin_amdgcn_mfma_f32_16x16x32_bf16(ag[mt][kk], bn[kk], acc, 0, 0, 0);
#pragma unroll
      for (int reg = 0; reg < 4; reg++) {
        int node = w0 + mt * 16 + q * 4 + reg;
        if (node < N_NODES) out[(long)node * D_FEAT + ncol] = acc[reg] + bv;
      }
    }
  }
}

extern "C" void kernel_launch(void* const* d_in, const int* in_sizes, int n_in,
                              void* d_out, int out_size, void* d_ws, size_t ws_size,
                              hipStream_t stream) {
  const float* x = (const float*)d_in[0];
  const int* ei = (const int*)d_in[1];         // int32
  const float* Wself = (const float*)d_in[2];
  const float* Wnb = (const float*)d_in[3];
  const float* bias = (const float*)d_in[4];
  float* out = (float*)d_out;

  auto alignup = [](size_t v) { return (v + 511) & ~(size_t)511; };
  char* p = (char*)d_ws;
  int* deg = (int*)p;            p += alignup((size_t)N_NODES * 4);
  int* row_start = (int*)p;      p += alignup((size_t)N_NODES * 4);
  float* dis = (float*)p;        p += alignup((size_t)N_NODES * 4);
  int* gcur = (int*)p;           p += alignup((size_t)BUCKETS * 4);
  u16* Wbf = (u16*)p;            p += alignup((size_t)4096 * 8 * 2);          // 64 KB
  int* cn = (int*)p;             p += alignup((size_t)BUCKETS * BKCAP * 4);   // 8.4 MB
  u16* xb = (u16*)p;             p += alignup((size_t)N_NODES * D_FEAT * 2);  // 25.6 MB
  u16* aggb = (u16*)p;           p += alignup((size_t)N_NODES * D_FEAT * 2);  // 25.6 MB
  // ~61 MB of d_ws (<= proven 66 MB footprint)
  u32* binrec = (u32*)d_out;     // 8.4 MB staged in d_out; dead before k_gemm writes it

  k_conv<<<KCONV_WGS, 256, 0, stream>>>((const float4*)x, (uint2*)xb, Wself, Wnb, Wbf, gcur);
  k_bin<<<BIN_WGS, 256, 0, stream>>>(ei, gcur, binrec);
  k_csr<<<BUCKETS, 256, 0, stream>>>(gcur, binrec, deg, row_start, dis, cn);
  k_agg<<<(N_NODES + 3) / 4, 256, 0, stream>>>(row_start, deg, dis, cn, (const u32*)xb, (u32*)aggb);
  k_gemm<<<(N_NODES + 127) / 128, 256, 0, stream>>>(xb, aggb, Wbf, bias, out);
}

// Round 13
// 236.437 us; speedup vs baseline: 1.1358x; 1.0328x over previous
//
#include <hip/hip_runtime.h>

#define N_NODES 100000
#define N_EDGES 1600000
#define D_FEAT 128
#define BUCKETS 512
#define RPB 196            /* rows per bucket; 512*196 = 100352 >= 100000 */
#define BKCAP 4096         /* fixed region; mean 3136, sd ~56, +17sd */
#define BIN_CHUNK 8192
#define BIN_WGS ((N_EDGES + BIN_CHUNK - 1) / BIN_CHUNK)  /* 196 */

#define CONV_ELEMS (N_NODES * D_FEAT / 4)                /* 3.2M float4 */
#define CONV_WGS 2048                                    /* grid-stride, fat blocks */
#define WPREP_WGS 16
/* merged grid: bin first (latency-critical, dispatched first), then wprep, then conv */
#define PREB_WGS (BIN_WGS + WPREP_WGS + CONV_WGS)

typedef unsigned int u32;
typedef unsigned short u16;
typedef __attribute__((ext_vector_type(8))) short bf16x8;
typedef __attribute__((ext_vector_type(4))) float f32x4;

__device__ inline float bfbits2f(u32 hi) { union { u32 u; float f; } v; v.u = hi; return v.f; }
__device__ inline float bflo(u32 pair) { return bfbits2f(pair << 16); }
__device__ inline float bfhi(u32 pair) { return bfbits2f(pair & 0xFFFF0000u); }
__device__ inline u16 f2bf(float f) {
  union { float f; u32 u; } v; v.f = f;
  u32 r = v.u + 0x7FFFu + ((v.u >> 16) & 1u);
  return (u16)(r >> 16);
}
__device__ inline int clampN(int v) { return ((unsigned)v < N_NODES) ? v : 0; }

// ---- merged front-end: edge binning | weight prep | x->bf16 conv ----
// bin and conv are data-independent: merging overlaps bin's LDS/latency
// phase under conv's HBM stream (separate pipes co-schedule, sum->max).
// Bin blocks take low blockIdx (dispatch first); conv keeps grid-stride
// FAT blocks so the 55KB-LDS occupancy cap (2 blocks/CU) costs stream
// turnover, not block turnover (R9's actual failure mode).
__global__ __launch_bounds__(256) void k_preb(const int* __restrict__ ei,
                                              int* __restrict__ gcur,
                                              u32* __restrict__ binrec,
                                              const float4* __restrict__ x4,
                                              uint2* __restrict__ xb2,
                                              const float* __restrict__ Wself,
                                              const float* __restrict__ Wnb,
                                              u16* __restrict__ Wbf) {
  __shared__ int hist[BUCKETS], pref[BUCKETS], lcur[BUCKETS], ps[256];
  __shared__ u32 stag[BIN_CHUNK];
  __shared__ u16 sbkt[BIN_CHUNK];
  int b = blockIdx.x;
  int tid = threadIdx.x;
  if (b >= BIN_WGS + WPREP_WGS) {
    // ---- conv: grid-stride over 3.2M float4 ----
    int cb = b - BIN_WGS - WPREP_WGS;
    for (int i = cb * 256 + tid; i < CONV_ELEMS; i += CONV_WGS * 256) {
      float4 v = x4[i];
      uint2 o;
      o.x = (u32)f2bf(v.x) | ((u32)f2bf(v.y) << 16);
      o.y = (u32)f2bf(v.z) | ((u32)f2bf(v.w) << 16);
      xb2[i] = o;
    }
    return;
  }
  if (b >= BIN_WGS) {
    // ---- weight prep: 4096 B-fragment entries ----
    int f = (b - BIN_WGS) * 256 + tid;
    int lane = f & 63, nt = (f >> 6) & 7, kk = (f >> 9) & 3, t = f >> 11;
    int q = lane >> 4, l16 = lane & 15;
    const float* W = t ? Wnb : Wself;
    int n = nt * 16 + l16;
    int k0 = (kk * 4 + q) * 8;
    u16 tmp[8];
#pragma unroll
    for (int j = 0; j < 8; j++) tmp[j] = f2bf(W[(k0 + j) * 128 + n]);
    uint4 o;
    o.x = (u32)tmp[0] | ((u32)tmp[1] << 16);
    o.y = (u32)tmp[2] | ((u32)tmp[3] << 16);
    o.z = (u32)tmp[4] | ((u32)tmp[5] << 16);
    o.w = (u32)tmp[6] | ((u32)tmp[7] << 16);
    *(uint4*)(Wbf + (long)f * 8) = o;
    return;
  }
  // ---- binning: WG-local LDS counting sort, bucket-contiguous flush ----
  long e0 = (long)b * BIN_CHUNK;
  for (int k = tid; k < BUCKETS; k += 256) { hist[k] = 0; lcur[k] = 0; }
  __syncthreads();
  int rows[BIN_CHUNK / 256];
#pragma unroll
  for (int j = 0; j < BIN_CHUNK / 256; j++) {
    long e = e0 + j * 256 + tid;
    int r = (e < N_EDGES) ? clampN(ei[e]) : -1;
    rows[j] = r;
    if (r >= 0) atomicAdd(&hist[r / RPB], 1);
  }
  __syncthreads();
  // scan 512 bins with 256 threads (2 bins/thread)
  int v0 = hist[2 * tid], v1 = hist[2 * tid + 1];
  int s = v0 + v1;
  ps[tid] = s;
  __syncthreads();
  for (int off = 1; off < 256; off <<= 1) {
    int t = (tid >= off) ? ps[tid - off] : 0;
    __syncthreads();
    ps[tid] += t;
    __syncthreads();
  }
  int excl = ps[tid] - s;
  pref[2 * tid] = excl;
  pref[2 * tid + 1] = excl + v0;
  // reserve global ranges; reuse hist as absolute gbase
  hist[2 * tid] = (2 * tid) * BKCAP + (v0 ? atomicAdd(&gcur[2 * tid], v0) : 0);
  hist[2 * tid + 1] = (2 * tid + 1) * BKCAP + (v1 ? atomicAdd(&gcur[2 * tid + 1], v1) : 0);
  int total = ps[255];
  __syncthreads();
#pragma unroll
  for (int j = 0; j < BIN_CHUNK / 256; j++) {
    int r = rows[j];
    if (r < 0) continue;
    long e = e0 + j * 256 + tid;
    int c = clampN(ei[N_EDGES + e]);
    int bk = r / RPB;
    int rl = r - bk * RPB;
    int pos = pref[bk] + atomicAdd(&lcur[bk], 1);
    stag[pos] = ((u32)rl << 17) | (u32)c;
    sbkt[pos] = (u16)bk;
  }
  __syncthreads();
  for (int i = tid; i < total; i += 256) {
    int bk = sbkt[i];
    int idx = hist[bk] + (i - pref[bk]);            // hist = absolute gbase
    if (idx < (bk + 1) * BKCAP) binrec[idx] = stag[i];   // overflow guard
  }
}

// ---- merged CSR: per-bucket hist + scan -> deg/row_start/dis, then
//      in-LDS placement -> coalesced cn (col only; norm computed in k_agg).
__global__ __launch_bounds__(256) void k_csr(const int* __restrict__ gcur,
                                             const u32* __restrict__ binrec,
                                             int* __restrict__ deg,
                                             int* __restrict__ row_start,
                                             float* __restrict__ dis,
                                             int* __restrict__ cn) {
  __shared__ int h[256];      // per-row counts (RPB=196, padded); scan in-place
  __shared__ int cur[256];    // placement cursors
  __shared__ int win[BKCAP];  // 16 KB staging window
  int tid = threadIdx.x;
  int b = blockIdx.x;
  int r0 = b * RPB;
  int nrows = N_NODES - r0; if (nrows > RPB) nrows = RPB; if (nrows < 0) nrows = 0;
  int base = b * BKCAP;
  int cnt = gcur[b]; if (cnt > BKCAP) cnt = BKCAP;
  h[tid] = 0;
  __syncthreads();
  for (int i = tid; i < cnt; i += 256) {
    u32 rec = binrec[base + i];
    atomicAdd(&h[rec >> 17], 1);
  }
  __syncthreads();
  int v = h[tid];
  __syncthreads();
  for (int off = 1; off < 256; off <<= 1) {
    int t = (tid >= off) ? h[tid - off] : 0;
    __syncthreads();
    h[tid] += t;
    __syncthreads();
  }
  int excl = h[tid] - v;
  cur[tid] = excl;
  if (tid < nrows) {
    int r = r0 + tid;
    deg[r] = v;
    row_start[r] = base + excl;
    dis[r] = v ? rsqrtf((float)v) : 0.0f;
  }
  __syncthreads();
  for (int i = tid; i < cnt; i += 256) {
    u32 rec = binrec[base + i];
    int rl = rec >> 17;
    int p = atomicAdd(&cur[rl], 1);
    win[p] = (int)(rec & 0x1FFFF);
  }
  __syncthreads();
  for (int i = tid; i < cnt; i += 256) cn[base + i] = win[i];
}

// -------- aggregation: aggb[r] = bf16( sum_e dis[r]*dis[c] * xb[c] ) --------
// R2-proven structure: 1 row/wave, u32/lane full-row gather, batch-8,
// exact tail tiers. norm computed on the fly (dis broadcast loads, L2-hot).
__global__ __launch_bounds__(256) void k_agg(const int* __restrict__ row_start,
                                             const int* __restrict__ deg,
                                             const float* __restrict__ dis,
                                             const int* __restrict__ cn,
                                             const u32* __restrict__ xb /* pairs, stride 64 */,
                                             u32* __restrict__ aggb) {
  int wave = threadIdx.x >> 6, lane = threadIdx.x & 63;
  int r = blockIdx.x * 4 + wave;
  if (r >= N_NODES) return;
  int start = row_start[r];
  int cnt = deg[r];
  float dr = dis[r];
  float a0 = 0.f, a1 = 0.f, b0 = 0.f, b1 = 0.f;
  int i = 0;
  for (; i + 8 <= cnt; i += 8) {
    int c[8];
    u32 g[8];
    float nc[8];
#pragma unroll
    for (int j = 0; j < 8; j++) c[j] = cn[start + i + j];
#pragma unroll
    for (int j = 0; j < 8; j++) g[j] = xb[(long)c[j] * 64 + lane];
#pragma unroll
    for (int j = 0; j < 8; j++) nc[j] = dis[c[j]];
#pragma unroll
    for (int j = 0; j < 8; j++) {
      float n = dr * nc[j];
      if (j & 1) { b0 += n * bflo(g[j]); b1 += n * bfhi(g[j]); }
      else       { a0 += n * bflo(g[j]); a1 += n * bfhi(g[j]); }
    }
  }
  for (; i + 2 <= cnt; i += 2) {
    int c0 = cn[start + i], c1 = cn[start + i + 1];
    u32 g0 = xb[(long)c0 * 64 + lane];
    u32 g1 = xb[(long)c1 * 64 + lane];
    float n0 = dr * dis[c0], n1 = dr * dis[c1];
    a0 += n0 * bflo(g0); a1 += n0 * bfhi(g0);
    b0 += n1 * bflo(g1); b1 += n1 * bfhi(g1);
  }
  if (i < cnt) {
    int c0 = cn[start + i];
    u32 g0 = xb[(long)c0 * 64 + lane];
    float n0 = dr * dis[c0];
    a0 += n0 * bflo(g0); a1 += n0 * bfhi(g0);
  }
  a0 += b0; a1 += b1;
  aggb[(long)r * 64 + lane] = (u32)f2bf(a0) | ((u32)f2bf(a1) << 16);
}

// -------- GEMM: out = x@Wself + agg@Wnb + bias. No LDS; B-frags from global ----
__global__ __launch_bounds__(256) void k_gemm(const u16* __restrict__ xb,
                                              const u16* __restrict__ aggb,
                                              const u16* __restrict__ Wbf,
                                              const float* __restrict__ bias,
                                              float* __restrict__ out) {
  int tid = threadIdx.x;
  int wave = tid >> 6, lane = tid & 63;
  int q = lane >> 4, l16 = lane & 15;
  int w0 = blockIdx.x * 128 + wave * 32;

  bf16x8 ax[2][4], ag[2][4];
#pragma unroll
  for (int mt = 0; mt < 2; mt++) {
    int node = w0 + mt * 16 + l16;
    long aoff = (long)clampN(node) * D_FEAT + q * 8;
#pragma unroll
    for (int kk = 0; kk < 4; kk++) {
      ax[mt][kk] = *(const bf16x8*)(xb + aoff + kk * 32);
      ag[mt][kk] = *(const bf16x8*)(aggb + aoff + kk * 32);
    }
  }

#pragma unroll
  for (int nt = 0; nt < 8; nt++) {
    bf16x8 bs[4], bn[4];
#pragma unroll
    for (int kk = 0; kk < 4; kk++) {
      bs[kk] = *(const bf16x8*)(Wbf + (long)(((0 * 4 + kk) * 8 + nt) * 64 + lane) * 8);
      bn[kk] = *(const bf16x8*)(Wbf + (long)(((1 * 4 + kk) * 8 + nt) * 64 + lane) * 8);
    }
    int ncol = nt * 16 + l16;
    float bv = bias[ncol];
#pragma unroll
    for (int mt = 0; mt < 2; mt++) {
      f32x4 acc = {0.f, 0.f, 0.f, 0.f};
#pragma unroll
      for (int kk = 0; kk < 4; kk++)
        acc = __builtin_amdgcn_mfma_f32_16x16x32_bf16(ax[mt][kk], bs[kk], acc, 0, 0, 0);
#pragma unroll
      for (int kk = 0; kk < 4; kk++)
        acc = __builtin_amdgcn_mfma_f32_16x16x32_bf16(ag[mt][kk], bn[kk], acc, 0, 0, 0);
#pragma unroll
      for (int reg = 0; reg < 4; reg++) {
        int node = w0 + mt * 16 + q * 4 + reg;
        if (node < N_NODES) out[(long)node * D_FEAT + ncol] = acc[reg] + bv;
      }
    }
  }
}

extern "C" void kernel_launch(void* const* d_in, const int* in_sizes, int n_in,
                              void* d_out, int out_size, void* d_ws, size_t ws_size,
                              hipStream_t stream) {
  const float* x = (const float*)d_in[0];
  const int* ei = (const int*)d_in[1];         // int32
  const float* Wself = (const float*)d_in[2];
  const float* Wnb = (const float*)d_in[3];
  const float* bias = (const float*)d_in[4];
  float* out = (float*)d_out;

  auto alignup = [](size_t v) { return (v + 511) & ~(size_t)511; };
  char* p = (char*)d_ws;
  int* deg = (int*)p;            p += alignup((size_t)N_NODES * 4);
  int* row_start = (int*)p;      p += alignup((size_t)N_NODES * 4);
  float* dis = (float*)p;        p += alignup((size_t)N_NODES * 4);
  int* gcur = (int*)p;           p += alignup((size_t)BUCKETS * 4);
  u16* Wbf = (u16*)p;            p += alignup((size_t)4096 * 8 * 2);          // 64 KB
  int* cn = (int*)p;             p += alignup((size_t)BUCKETS * BKCAP * 4);   // 8.4 MB
  u16* xb = (u16*)p;             p += alignup((size_t)N_NODES * D_FEAT * 2);  // 25.6 MB
  u16* aggb = (u16*)p;           p += alignup((size_t)N_NODES * D_FEAT * 2);  // 25.6 MB
  // ~61 MB of d_ws (<= proven 66 MB footprint)
  u32* binrec = (u32*)d_out;     // 8.4 MB staged in d_out; dead before k_gemm writes it

  hipMemsetAsync(gcur, 0, (size_t)BUCKETS * 4, stream);

  k_preb<<<PREB_WGS, 256, 0, stream>>>(ei, gcur, binrec, (const float4*)x, (uint2*)xb,
                                       Wself, Wnb, Wbf);
  k_csr<<<BUCKETS, 256, 0, stream>>>(gcur, binrec, deg, row_start, dis, cn);
  k_agg<<<(N_NODES + 3) / 4, 256, 0, stream>>>(row_start, deg, dis, cn, (const u32*)xb, (u32*)aggb);
  k_gemm<<<(N_NODES + 127) / 128, 256, 0, stream>>>(xb, aggb, Wbf, bias, out);
}